// Round 2
// baseline (160.215 us; speedup 1.0000x reference)
//
#include <hip/hip_runtime.h>
#include <math.h>

#define H2 256
#define MAXDEG 128
#define APAD 520   // sA row stride (halves): 1040B rows -> 2-way banks (free)
#define HPAD 264   // hbuf row stride (halves): 528B rows -> 2-way banks (free)

typedef _Float16 f16x8 __attribute__((ext_vector_type(8)));
typedef _Float16 f16x4 __attribute__((ext_vector_type(4)));
typedef float f32x4 __attribute__((ext_vector_type(4)));

// ---------------------------------------------------------------------------
// Fused prep: zero cursor; nf fp32 -> catfull[:, 0:256) fp16 (row stride 512);
// W1[512][256]->W1t[256][512] fp16; W2[256][256]->W2t[256][256] fp16.
__global__ __launch_bounds__(256) void prep(
        const float* __restrict__ nf, const float* __restrict__ W1,
        const float* __restrict__ W2, int* __restrict__ cursor,
        _Float16* __restrict__ catfull, _Float16* __restrict__ W1t,
        _Float16* __restrict__ W2t, int n) {
    int flat = blockIdx.x * 256 + threadIdx.x;
    if (flat < n) cursor[flat] = 0;
    if (flat < 512 * 256) {                    // W1t idx = nn*512 + k
        int nn = flat >> 9, k = flat & 511;
        W1t[flat] = (_Float16)W1[(size_t)k * 256 + nn];
    } else if (flat < 512 * 256 + 256 * 256) { // W2t idx2 = nn*256 + k
        int idx2 = flat - 512 * 256;
        int nn = idx2 >> 8, k = idx2 & 255;
        W2t[idx2] = (_Float16)W2[(size_t)k * 256 + nn];
    }
    int wid  = threadIdx.x >> 6;
    int lane = threadIdx.x & 63;
    int row  = blockIdx.x * 4 + wid;
    if (row < n) {
        float4 v = ((const float4*)nf)[(size_t)row * 64 + lane];
        f16x4 h;
        h.x = (_Float16)v.x; h.y = (_Float16)v.y;
        h.z = (_Float16)v.z; h.w = (_Float16)v.w;
        *(f16x4*)&catfull[(size_t)row * 512 + lane * 4] = h;
    }
}

// ---------------------------------------------------------------------------
__global__ void scatter_edges(const int* __restrict__ esrc, const int* __restrict__ edst,
                              int* __restrict__ cursor, int* __restrict__ bucket, int E) {
    int e = blockIdx.x * 256 + threadIdx.x;
    if (e >= E) return;
    int d = edst[e];
    int s = esrc[e];
    int r = atomicAdd(&cursor[d], 1);
    if (r < MAXDEG) bucket[d * MAXDEG + r] = s;
}

// ---------------------------------------------------------------------------
// Panel-split gather: the gathered working set (cat fp16 self-half, 5.1 MB)
// does not fit one XCD's 4 MB L2, so full-row random gathers are served by
// L3 at random-access BW. Split the 256 cols into 2 panels of 128 cols
// (2.56 MB working set each) and pin panel -> XCD half via the round-robin
// blockIdx%8 dispatch mapping: XCDs 0-3 gather only panel 0, XCDs 4-7 only
// panel 1 -> gathers become L2 hits. Per wave: one (node, panel); two
// 32-lane groups process 2 edges in parallel (8 B/lane, 256 B per gathered
// panel-row), 4 edge-pairs in flight per iteration; one shfl_xor(32)
// cross-group reduce. Streaming data (cursor, bucket) uses non-temporal
// loads; pooled output uses a non-temporal store, keeping L2 for the panel.
__global__ __launch_bounds__(256) void gather(
        const float* __restrict__ nf, const int* __restrict__ cursor,
        const int* __restrict__ bucket, _Float16* __restrict__ catfull, int M) {
    int lane = threadIdx.x & 63, wid = threadIdx.x >> 6;
    int b = blockIdx.x;
    int xcd = b & 7;
    int p = xcd >> 2;                   // panel 0/1 pinned to XCD halves
    int i = (b >> 3) * 4 + (xcd & 3);   // node-group id within panel
    int node = i * 4 + wid;
    if (node >= M) return;
    int g = lane >> 5;                  // edge-slot group 0/1
    int c = lane & 31;                  // column quad within panel
    int pc = p * 128 + c * 4;           // column offset (halves)

    int deg  = __builtin_nontemporal_load(&cursor[node]);
    int degc = deg < MAXDEG ? deg : MAXDEG;
    const int* bk = bucket + (size_t)node * MAXDEG;

    float4 acc[4];
#pragma unroll
    for (int k = 0; k < 4; ++k) acc[k] = make_float4(0.f, 0.f, 0.f, 0.f);

    for (int e = 0; e < degc; e += 8) {
#pragma unroll
        for (int k = 0; k < 4; ++k) {
            int idx = e + 2 * k + g;
            int ii  = idx < degc ? idx : degc - 1;   // in-bounds duplicate
            int s   = __builtin_nontemporal_load(&bk[ii]);
            f16x4 v = *(const f16x4*)&catfull[(size_t)s * 512 + pc];
            float m = idx < degc ? 1.0f : 0.0f;      // zero padded slots
            acc[k].x += m * (float)v.x;
            acc[k].y += m * (float)v.y;
            acc[k].z += m * (float)v.z;
            acc[k].w += m * (float)v.w;
        }
    }

    float4 t;
    t.x = (acc[0].x + acc[1].x) + (acc[2].x + acc[3].x);
    t.y = (acc[0].y + acc[1].y) + (acc[2].y + acc[3].y);
    t.z = (acc[0].z + acc[1].z) + (acc[2].z + acc[3].z);
    t.w = (acc[0].w + acc[1].w) + (acc[2].w + acc[3].w);
    // combine the two edge-slot groups (lane ^ 32)
    t.x += __shfl_xor(t.x, 32);
    t.y += __shfl_xor(t.y, 32);
    t.z += __shfl_xor(t.z, 32);
    t.w += __shfl_xor(t.w, 32);

    if (g == 0) {
        float4 self = ((const float4*)nf)[(size_t)node * 64 + p * 32 + c];
        float fd = (float)deg;
        f16x4 o;
        o.x = (_Float16)(fd * self.x - t.x);
        o.y = (_Float16)(fd * self.y - t.y);
        o.z = (_Float16)(fd * self.z - t.z);
        o.w = (_Float16)(fd * self.w - t.w);
        __builtin_nontemporal_store(o, (f16x4*)&catfull[(size_t)node * 512 + 256 + pc]);
    }
}

// ---------------------------------------------------------------------------
// Pure 2-stage GEMM: out = tanh((catfull @ W1t + b1) @ W2t + b2).
// 512 thr / 8 waves; M-tile 16 (grid 625); wave n-tile 32.
// Stage A rows straight from catfull (b128, 2 passes). W fragments from L2
// via depth-4 register pipeline; A via LDS with 1-step prefetch; h via LDS.
__global__ __launch_bounds__(512, 4) void gemm12(
        const _Float16* __restrict__ catfull,
        const _Float16* __restrict__ W1t, const _Float16* __restrict__ W2t,
        const float* __restrict__ b1, const float* __restrict__ b2,
        float* __restrict__ out, int M) {
    __shared__ _Float16 sA[16 * APAD];     // 16.3 KB
    __shared__ _Float16 hbuf[16 * HPAD];   //  8.3 KB

    int tid = threadIdx.x, lane = tid & 63, wid = tid >> 6;   // wid 0..7
    int m0 = blockIdx.x * 16;
    int wn = wid * 32;
    int fm = lane & 15;
    int q  = lane >> 4;
    int fk = q * 8;

    // ---- stage catfull rows -> sA: 16 rows x 64 b128 groups, 2 passes
    {
        int idx = tid;
#pragma unroll
        for (int p = 0; p < 2; ++p, idx += 512) {
            int row = idx >> 6, g = (idx & 63) * 8;
            int r = m0 + row; if (r >= M) r = M - 1;
            *(uint4*)&sA[row * APAD + g] = *(const uint4*)&catfull[(size_t)r * 512 + g];
        }
    }
    __syncthreads();

    // ---- stage 1: h[16][256] = sA @ W1t + b1 ----
    size_t brow[2];
#pragma unroll
    for (int j = 0; j < 2; ++j) brow[j] = (size_t)(wn + j * 16 + fm) * 512 + fk;

    f16x8 wp[4][2];
#pragma unroll
    for (int s = 0; s < 4; ++s)
#pragma unroll
        for (int j = 0; j < 2; ++j)
            wp[s][j] = *(const f16x8*)&W1t[brow[j] + s * 32];

    f32x4 acc[2] = {};
    f16x8 a_cur = *(const f16x8*)&sA[fm * APAD + fk];
#pragma unroll
    for (int kb = 0; kb < 512; kb += 32) {
        int slot = (kb >> 5) & 3;
        f16x8 a_nxt;
        if (kb + 32 < 512) a_nxt = *(const f16x8*)&sA[fm * APAD + kb + 32 + fk];
        f16x8 w0 = wp[slot][0], w1 = wp[slot][1];
        if (kb + 128 < 512) {
            wp[slot][0] = *(const f16x8*)&W1t[brow[0] + kb + 128];
            wp[slot][1] = *(const f16x8*)&W1t[brow[1] + kb + 128];
        }
        acc[0] = __builtin_amdgcn_mfma_f32_16x16x32_f16(a_cur, w0, acc[0], 0, 0, 0);
        acc[1] = __builtin_amdgcn_mfma_f32_16x16x32_f16(a_cur, w1, acc[1], 0, 0, 0);
        if (kb + 32 < 512) a_cur = a_nxt;
    }

    // epilogue 1: hbuf[row][ncol], row = q*4+r, ncol = wn + j*16 + fm
#pragma unroll
    for (int j = 0; j < 2; ++j) {
        int ncol = wn + j * 16 + fm;
        float bv = b1[ncol];
#pragma unroll
        for (int r = 0; r < 4; ++r)
            hbuf[(q * 4 + r) * HPAD + ncol] = (_Float16)(acc[j][r] + bv);
    }
    __syncthreads();

    // ---- stage 2: out[16][256] = tanh(h @ W2t + b2) ----
    size_t brow2[2];
#pragma unroll
    for (int j = 0; j < 2; ++j) brow2[j] = (size_t)(wn + j * 16 + fm) * 256 + fk;

#pragma unroll
    for (int s = 0; s < 4; ++s)
#pragma unroll
        for (int j = 0; j < 2; ++j)
            wp[s][j] = *(const f16x8*)&W2t[brow2[j] + s * 32];

    f32x4 acc2[2] = {};
    a_cur = *(const f16x8*)&hbuf[fm * HPAD + fk];
#pragma unroll
    for (int kb = 0; kb < 256; kb += 32) {
        int slot = (kb >> 5) & 3;
        f16x8 a_nxt;
        if (kb + 32 < 256) a_nxt = *(const f16x8*)&hbuf[fm * HPAD + kb + 32 + fk];
        f16x8 w0 = wp[slot][0], w1 = wp[slot][1];
        if (kb + 128 < 256) {
            wp[slot][0] = *(const f16x8*)&W2t[brow2[0] + kb + 128];
            wp[slot][1] = *(const f16x8*)&W2t[brow2[1] + kb + 128];
        }
        acc2[0] = __builtin_amdgcn_mfma_f32_16x16x32_f16(a_cur, w0, acc2[0], 0, 0, 0);
        acc2[1] = __builtin_amdgcn_mfma_f32_16x16x32_f16(a_cur, w1, acc2[1], 0, 0, 0);
        if (kb + 32 < 256) a_cur = a_nxt;
    }

    // epilogue 2
#pragma unroll
    for (int j = 0; j < 2; ++j) {
        int ncol = wn + j * 16 + fm;
        float bv = b2[ncol];
#pragma unroll
        for (int r = 0; r < 4; ++r) {
            int row = m0 + q * 4 + r;
            if (row < M) out[(size_t)row * 256 + ncol] = tanhf(acc2[j][r] + bv);
        }
    }
}

// ---------------------------------------------------------------------------
extern "C" void kernel_launch(void* const* d_in, const int* in_sizes, int n_in,
                              void* d_out, int out_size, void* d_ws, size_t ws_size,
                              hipStream_t stream) {
    const float* nf  = (const float*)d_in[0];   // [N, 256] fp32
    const float* W1  = (const float*)d_in[1];   // [512, 256]
    const float* b1  = (const float*)d_in[2];   // [256]
    const float* W2  = (const float*)d_in[3];   // [256, 256]
    const float* b2  = (const float*)d_in[4];   // [256]
    const int* esrc  = (const int*)d_in[5];     // [E]
    const int* edst  = (const int*)d_in[6];     // [E]
    float* out = (float*)d_out;                 // [N, 256] fp32

    int N = in_sizes[0] / H2;
    int E = in_sizes[5];

    char* ws = (char*)d_ws;
    size_t off = 0;
    auto take = [&](size_t bytes) { size_t o = off; off += (bytes + 255) / 256 * 256; return o; };
    int*       cursor  = (int*)(ws + take((size_t)N * 4));
    int*       bucket  = (int*)(ws + take((size_t)N * MAXDEG * 4));
    _Float16*  catfull = (_Float16*)(ws + take((size_t)N * 512 * 2));
    _Float16*  W1t     = (_Float16*)(ws + take(512 * 256 * 2));
    _Float16*  W2t     = (_Float16*)(ws + take(256 * 256 * 2));

    prep<<<(N + 3) / 4, 256, 0, stream>>>(nf, W1, W2, cursor, catfull, W1t, W2t, N);
    scatter_edges<<<(E + 255) / 256, 256, 0, stream>>>(esrc, edst, cursor, bucket, E);

    int node_groups = (N + 3) / 4;
    int gather_grid = ((2 * node_groups + 7) / 8) * 8;   // 2 panels, XCD-pinned
    gather<<<gather_grid, 256, 0, stream>>>(nf, cursor, bucket, catfull, N);

    gemm12<<<(N + 15) / 16, 512, 0, stream>>>(catfull, W1t, W2t, b1, b2, out, N);
}